// Round 15
// baseline (562.570 us; speedup 1.0000x reference)
//
#include <hip/hip_runtime.h>

#define NN 100000
#define NE 640000
#define NB_SCAN 98   // ceil(NN/1024)

typedef __attribute__((ext_vector_type(8))) short short8;
typedef __attribute__((ext_vector_type(4))) float f32x4;
typedef __attribute__((ext_vector_type(4))) ushort ushort4v;

__device__ __forceinline__ float bf2f(ushort u) {
    unsigned v = ((unsigned)u) << 16;
    return __builtin_bit_cast(float, v);
}
__device__ __forceinline__ ushort f2bf(float f) {
    unsigned u = __builtin_bit_cast(unsigned, f);
    u += 0x7fffu + ((u >> 16) & 1u);   // RNE
    return (ushort)(u >> 16);
}
__device__ __forceinline__ short8 brelu(short8 v) {
    #pragma unroll
    for (int i = 0; i < 8; ++i) v[i] = (v[i] < (short)0) ? (short)0 : v[i];
    return v;
}

// ======================= CSR build (topology, once per call) ================
__global__ void k_hist(const int* __restrict__ dst, int* __restrict__ hist)
{
    int i = blockIdx.x * 256 + threadIdx.x;   // NE threads
    atomicAdd(&hist[dst[i]], 1);
}

__global__ __launch_bounds__(256) void k_scan_part(const int* __restrict__ hist,
                                                   int* __restrict__ rp,
                                                   int* __restrict__ parts)
{
    __shared__ int s[256];
    int b = blockIdx.x, t = threadIdx.x;
    int base = b * 1024 + t * 4;
    int v[4]; int sum = 0;
    #pragma unroll
    for (int i = 0; i < 4; ++i) { int idx = base + i; v[i] = (idx < NN) ? hist[idx] : 0; sum += v[i]; }
    s[t] = sum; __syncthreads();
    for (int off = 1; off < 256; off <<= 1) {
        int x = (t >= off) ? s[t - off] : 0;
        __syncthreads(); s[t] += x; __syncthreads();
    }
    int excl = s[t] - sum;
    if (t == 255) parts[b] = s[255];
    int run = excl;
    #pragma unroll
    for (int i = 0; i < 4; ++i) { int idx = base + i; if (idx < NN) rp[idx] = run; run += v[i]; }
}

__global__ void k_scan_tops(int* __restrict__ parts, int* __restrict__ rp)
{
    __shared__ int s[128];
    int t = threadIdx.x;   // 128 threads
    int v = (t < NB_SCAN) ? parts[t] : 0;
    s[t] = v; __syncthreads();
    for (int off = 1; off < 128; off <<= 1) {
        int x = (t >= off) ? s[t - off] : 0;
        __syncthreads(); s[t] += x; __syncthreads();
    }
    parts[t] = s[t] - v;   // exclusive
    if (t == 0) rp[NN] = NE;
}

__global__ __launch_bounds__(256) void k_scan_add(int* __restrict__ rp,
                                                  const int* __restrict__ parts,
                                                  int* __restrict__ cursor)
{
    int i = blockIdx.x * 256 + threadIdx.x;
    if (i >= NN) return;
    int v = rp[i] + parts[i >> 10];
    rp[i] = v; cursor[i] = v;
}

// eidx[p] = edge id at dst-sorted position p
__global__ void k_scatter(const int* __restrict__ dst,
                          int* __restrict__ cursor, int* __restrict__ eidx)
{
    int i = blockIdx.x * 256 + threadIdx.x;   // NE threads
    int d = dst[i];
    int p = atomicAdd(&cursor[d], 1);
    eidx[p] = i;
}

// ======================= weight prep =======================================
__global__ void k_w_subtile(const float* __restrict__ w, ushort* __restrict__ out,
                            int K, int Nin)
{
    int t = blockIdx.x * 256 + threadIdx.x;
    if (t >= K * 64) return;
    int k = t >> 6, c = t & 63;
    float v = (c < Nin) ? w[k * Nin + c] : 0.f;
    out[((k >> 3) * 64 + c) * 8 + (k & 7)] = f2bf(v);
}

__global__ void k_w_padk(const float* __restrict__ w, ushort* __restrict__ out,
                         int Kreal, int Kpad)
{
    int t = blockIdx.x * 256 + threadIdx.x;
    if (t >= Kpad * 64) return;
    int k = t >> 6, c = t & 63;
    float v = (k < Kreal) ? w[k * 64 + c] : 0.f;
    out[((k >> 3) * 64 + c) * 8 + (k & 7)] = f2bf(v);
}

__global__ void k_w_msg(const float* __restrict__ lw, ushort* __restrict__ out)
{
    int t = blockIdx.x * 256 + threadIdx.x;   // 128*64
    if (t >= 128 * 64) return;
    int k = t >> 6, c = t & 63;
    float v = (k < 64) ? (k == c ? 1.f : 0.f) : lw[(k - 64) * 64 + c];
    out[((k >> 3) * 64 + c) * 8 + (k & 7)] = f2bf(v);
}

// ======================= node embedding ====================================
__global__ __launch_bounds__(256) void k_node_emb_mfma(
    const float* __restrict__ xin, const ushort* __restrict__ ws,
    const float* __restrict__ b, float* __restrict__ xout,
    ushort* __restrict__ xb)
{
    __shared__ ushort wl[32 * 64];
    __shared__ float fbuf[4][16 * 64];
    __shared__ ushort bbuf[4][16 * 64];
    int tid = threadIdx.x;
    *(short8*)&wl[tid * 8] = *(const short8*)&ws[tid * 8];
    __syncthreads();

    int wid = tid >> 6, lane = tid & 63, c = lane & 15, kg = lane >> 4;
    int t = blockIdx.x * 4 + wid;
    if (t >= NN / 16) return;
    int n0 = t * 16;

    const float* xr = xin + (size_t)(n0 + c) * 32 + kg * 8;
    f32x4 u0 = *(const f32x4*)xr, u1 = *(const f32x4*)(xr + 4);
    short8 a;
    #pragma unroll
    for (int j = 0; j < 4; ++j) { a[j] = (short)f2bf(u0[j]); a[4 + j] = (short)f2bf(u1[j]); }

    f32x4 acc[4];
    #pragma unroll
    for (int nt = 0; nt < 4; ++nt) {
        float bv = b[nt * 16 + c];
        acc[nt] = f32x4{bv, bv, bv, bv};
        short8 bf = *(const short8*)&wl[(kg * 64 + nt * 16 + c) * 8];
        acc[nt] = __builtin_amdgcn_mfma_f32_16x16x32_bf16(a, bf, acc[nt], 0, 0, 0);
    }
    #pragma unroll
    for (int nt = 0; nt < 4; ++nt)
        #pragma unroll
        for (int i = 0; i < 4; ++i) {
            int rr = kg * 4 + i, cc = nt * 16 + c;
            float v = acc[nt][i];
            fbuf[wid][rr * 64 + cc] = v;
            bbuf[wid][rr * 64 + cc] = f2bf(v);
        }
    #pragma unroll
    for (int r = 0; r < 4; ++r) {
        int q = r * 64 + lane;
        *(f32x4*)&xout[(size_t)(n0 + (q >> 4)) * 64 + (q & 15) * 4] =
            *(f32x4*)&fbuf[wid][q * 4];
    }
    #pragma unroll
    for (int r = 0; r < 2; ++r) {
        int q = r * 64 + lane;
        *(short8*)&xb[(size_t)(n0 + (q >> 3)) * 64 + (q & 7) * 8] =
            *(short8*)&bbuf[wid][q * 8];
    }
}

// ======================= edge embedding + layer-0 msg (fused) ==============
// e0 = eattr @ ew + eb;  msg0 = relu([x0[src] | e0] @ wms0 + lb0)
// msgbuf stored in EDGE order (coalesced); conv gathers via eidx.
__global__ __launch_bounds__(256) void k_edge_emb_fused(
    const float* __restrict__ ein, const ushort* __restrict__ ws,
    const float* __restrict__ b, ushort* __restrict__ eb,
    const ushort* __restrict__ xb, const int* __restrict__ src,
    const ushort* __restrict__ wm, const float* __restrict__ lb,
    ushort* __restrict__ msgbuf)
{
    __shared__ ushort wl[32 * 64];
    __shared__ ushort wml[128 * 64];
    __shared__ ushort bbuf[4][16 * 72];   // padded rows (72) for b128 readback
    int tid = threadIdx.x;
    *(short8*)&wl[tid * 8] = *(const short8*)&ws[tid * 8];
    #pragma unroll
    for (int i = 0; i < 4; ++i)
        *(short8*)&wml[(i * 256 + tid) * 8] = *(const short8*)&wm[(i * 256 + tid) * 8];
    __syncthreads();

    int wid = tid >> 6, lane = tid & 63, c = lane & 15, kg = lane >> 4;
    int e0 = (blockIdx.x * 4 + wid) * 16;
    ushort* bb = bbuf[wid];

    // prefetch x[src] early (random gather overlaps the e0 GEMM)
    const ushort* xs = xb + (size_t)src[e0 + c] * 64;
    short8 a0 = *(const short8*)(xs + kg * 8);
    short8 a1 = *(const short8*)(xs + 32 + kg * 8);

    // ---- e0 = emb(edge_attr), K padded 16->32 ----
    short8 a = (short8)0;
    if (kg < 2) {
        const float* er = ein + (size_t)(e0 + c) * 16 + kg * 8;
        f32x4 u0 = *(const f32x4*)er, u1 = *(const f32x4*)(er + 4);
        #pragma unroll
        for (int j = 0; j < 4; ++j) { a[j] = (short)f2bf(u0[j]); a[4 + j] = (short)f2bf(u1[j]); }
    }
    f32x4 acc[4];
    #pragma unroll
    for (int nt = 0; nt < 4; ++nt) {
        float bv = b[nt * 16 + c];
        acc[nt] = f32x4{bv, bv, bv, bv};
        short8 bf = *(const short8*)&wl[(kg * 64 + nt * 16 + c) * 8];
        acc[nt] = __builtin_amdgcn_mfma_f32_16x16x32_bf16(a, bf, acc[nt], 0, 0, 0);
    }
    #pragma unroll
    for (int nt = 0; nt < 4; ++nt)
        #pragma unroll
        for (int i = 0; i < 4; ++i)
            bb[(kg * 4 + i) * 72 + nt * 16 + c] = f2bf(acc[nt][i]);
    // coalesced eb store
    #pragma unroll
    for (int r = 0; r < 2; ++r) {
        int q = r * 64 + lane;
        *(short8*)&eb[(size_t)(e0 + (q >> 3)) * 64 + (q & 7) * 8] =
            *(short8*)&bb[(q >> 3) * 72 + (q & 7) * 8];
    }
    // ---- msg0 = relu([x|e0] @ wms + lb) ----
    short8 en0 = *(const short8*)&bb[c * 72 + kg * 8];
    short8 en1 = *(const short8*)&bb[c * 72 + 32 + kg * 8];

    f32x4 acc3[4];
    #pragma unroll
    for (int nt = 0; nt < 4; ++nt) {
        float bv = lb[nt * 16 + c];
        acc3[nt] = f32x4{bv, bv, bv, bv};
    }
    short8 af[4] = {a0, a1, en0, en1};
    #pragma unroll
    for (int ks = 0; ks < 4; ++ks) {
        #pragma unroll
        for (int nt = 0; nt < 4; ++nt) {
            short8 bf = *(const short8*)&wml[((ks * 4 + kg) * 64 + nt * 16 + c) * 8];
            acc3[nt] = __builtin_amdgcn_mfma_f32_16x16x32_bf16(af[ks], bf, acc3[nt], 0, 0, 0);
        }
    }
    #pragma unroll
    for (int nt = 0; nt < 4; ++nt)
        #pragma unroll
        for (int i = 0; i < 4; ++i)
            bb[(kg * 4 + i) * 72 + nt * 16 + c] = f2bf(fmaxf(acc3[nt][i], 0.f));
    // coalesced msgbuf store (edge order)
    #pragma unroll
    for (int r = 0; r < 2; ++r) {
        int q = r * 64 + lane;
        *(short8*)&msgbuf[(size_t)(e0 + (q >> 3)) * 64 + (q & 7) * 8] =
            *(short8*)&bb[(q >> 3) * 72 + (q & 7) * 8];
    }
}

// ======================= conv with CSR aggregation (gather msg rows) ========
// software-pipelined gather loop (prefetch row j+1 while accumulating j)
__global__ __launch_bounds__(256) void k_conv_csr(
    const float* __restrict__ x, const ushort* __restrict__ msgbuf,
    const int* __restrict__ rp, const int* __restrict__ eidx,
    float* __restrict__ hout,
    const ushort* __restrict__ w1s, const float* __restrict__ b1,
    const ushort* __restrict__ w2s, const float* __restrict__ b2,
    float* __restrict__ stats)
{
    __shared__ ushort w1l[64 * 64];
    __shared__ ushort w2l[64 * 64];
    __shared__ ushort h1l[4][1024];
    __shared__ float red[2][4][64];
    int tid = threadIdx.x;
    #pragma unroll
    for (int i = 0; i < 2; ++i) {
        *(short8*)&w1l[(i * 256 + tid) * 8] = *(const short8*)&w1s[(i * 256 + tid) * 8];
        *(short8*)&w2l[(i * 256 + tid) * 8] = *(const short8*)&w2s[(i * 256 + tid) * 8];
    }
    __syncthreads();

    int wid = tid >> 6, lane = tid & 63;
    int c = lane & 15, kg = lane >> 4;

    short8 w2f[2][4];
    #pragma unroll
    for (int ks = 0; ks < 2; ++ks)
        #pragma unroll
        for (int nt = 0; nt < 4; ++nt)
            w2f[ks][nt] = *(const short8*)&w2l[((ks * 4 + kg) * 64 + nt * 16 + c) * 8];

    float b1v[4], b2v[4];
    #pragma unroll
    for (int nt = 0; nt < 4; ++nt) { b1v[nt] = b1[nt * 16 + c]; b2v[nt] = b2[nt * 16 + c]; }

    float s1[4] = {0.f, 0.f, 0.f, 0.f}, s2[4] = {0.f, 0.f, 0.f, 0.f};
    ushort* hl = h1l[wid];

    int t = blockIdx.x * 4 + wid;
    if (t < NN / 16) {
        int n0 = t * 16;
        int n = n0 + c;
        int jb = rp[n], je = rp[n + 1];
        float sm0[8] = {0,0,0,0,0,0,0,0}, sm1[8] = {0,0,0,0,0,0,0,0};
        if (jb < je) {
            int row = eidx[jb];
            short8 m0 = *(const short8*)&msgbuf[(size_t)row * 64 + kg * 8];
            short8 m1 = *(const short8*)&msgbuf[(size_t)row * 64 + 32 + kg * 8];
            for (int j = jb + 1; j <= je; ++j) {
                short8 p0, p1;
                if (j < je) {
                    int nrow = eidx[j];
                    p0 = *(const short8*)&msgbuf[(size_t)nrow * 64 + kg * 8];
                    p1 = *(const short8*)&msgbuf[(size_t)nrow * 64 + 32 + kg * 8];
                }
                #pragma unroll
                for (int i = 0; i < 8; ++i) {
                    sm0[i] += bf2f((ushort)m0[i]);
                    sm1[i] += bf2f((ushort)m1[i]);
                }
                if (j < je) { m0 = p0; m1 = p1; }
            }
        }
        const float* xr = x + (size_t)n * 64;
        f32x4 u0 = *(const f32x4*)(xr + kg * 8);
        f32x4 u1 = *(const f32x4*)(xr + kg * 8 + 4);
        f32x4 v0 = *(const f32x4*)(xr + 32 + kg * 8);
        f32x4 v1 = *(const f32x4*)(xr + 32 + kg * 8 + 4);
        short8 a[2];
        #pragma unroll
        for (int j = 0; j < 4; ++j) {
            a[0][j]     = (short)f2bf(u0[j] + sm0[j]);
            a[0][4 + j] = (short)f2bf(u1[j] + sm0[4 + j]);
            a[1][j]     = (short)f2bf(v0[j] + sm1[j]);
            a[1][4 + j] = (short)f2bf(v1[j] + sm1[4 + j]);
        }
        f32x4 acc[4];
        #pragma unroll
        for (int nt = 0; nt < 4; ++nt) acc[nt] = f32x4{b1v[nt], b1v[nt], b1v[nt], b1v[nt]};
        #pragma unroll
        for (int ks = 0; ks < 2; ++ks) {
            #pragma unroll
            for (int nt = 0; nt < 4; ++nt) {
                short8 bf = *(const short8*)&w1l[((ks * 4 + kg) * 64 + nt * 16 + c) * 8];
                acc[nt] = __builtin_amdgcn_mfma_f32_16x16x32_bf16(a[ks], bf, acc[nt], 0, 0, 0);
            }
        }
        #pragma unroll
        for (int nt = 0; nt < 4; ++nt) {
            #pragma unroll
            for (int i = 0; i < 4; ++i) {
                int rr = kg * 4 + i, cc = nt * 16 + c;
                hl[((cc >> 3) * 16 + rr) * 8 + (cc & 7)] = f2bf(fmaxf(acc[nt][i], 0.f));
            }
        }
        f32x4 acc2[4];
        #pragma unroll
        for (int nt = 0; nt < 4; ++nt) acc2[nt] = f32x4{b2v[nt], b2v[nt], b2v[nt], b2v[nt]};
        #pragma unroll
        for (int ks = 0; ks < 2; ++ks) {
            short8 ha = *(const short8*)&hl[((ks * 4 + kg) * 16 + c) * 8];
            #pragma unroll
            for (int nt = 0; nt < 4; ++nt)
                acc2[nt] = __builtin_amdgcn_mfma_f32_16x16x32_bf16(ha, w2f[ks][nt], acc2[nt], 0, 0, 0);
        }
        #pragma unroll
        for (int nt = 0; nt < 4; ++nt) {
            #pragma unroll
            for (int i = 0; i < 4; ++i) {
                int rr = kg * 4 + i, cc = nt * 16 + c;
                float h2 = acc2[nt][i];
                hout[(size_t)(n0 + rr) * 64 + cc] = h2;
                s1[nt] += h2;
                s2[nt] += h2 * h2;
            }
        }
    }
    #pragma unroll
    for (int nt = 0; nt < 4; ++nt) {
        float v1 = s1[nt], v2 = s2[nt];
        v1 += __shfl_xor(v1, 16); v1 += __shfl_xor(v1, 32);
        v2 += __shfl_xor(v2, 16); v2 += __shfl_xor(v2, 32);
        s1[nt] = v1; s2[nt] = v2;
    }
    if (lane < 16) {
        #pragma unroll
        for (int nt = 0; nt < 4; ++nt) {
            red[0][wid][nt * 16 + c] = s1[nt];
            red[1][wid][nt * 16 + c] = s2[nt];
        }
    }
    __syncthreads();
    if (wid == 0) {
        float a = red[0][0][lane] + red[0][1][lane] + red[0][2][lane] + red[0][3][lane];
        float b = red[1][0][lane] + red[1][1][lane] + red[1][2][lane] + red[1][3][lane];
        unsafeAtomicAdd(&stats[lane], a);
        unsafeAtomicAdd(&stats[64 + lane], b);
    }
}

__global__ void k_bnfin(float* __restrict__ stats,
                        const float* __restrict__ gamma,
                        const float* __restrict__ beta)
{
    int j = threadIdx.x;
    float mu = stats[j] * (1.f / NN);
    float var = stats[64 + j] * (1.f / NN) - mu * mu;
    float a = gamma[j] * rsqrtf(var + 1e-5f);
    stats[128 + j] = a;
    stats[192 + j] = beta[j] - mu * a;
}

__global__ __launch_bounds__(256) void k_xupd4(float* __restrict__ x,
                                               const float* __restrict__ h,
                                               const float* __restrict__ stats,
                                               ushort* __restrict__ xb)
{
    int idx = blockIdx.x * 256 + threadIdx.x;   // NN*16 threads
    int j4 = (idx & 15) * 4;
    f32x4 hv = *(const f32x4*)&h[(size_t)idx * 4];
    f32x4 xv = *(const f32x4*)&x[(size_t)idx * 4];
    f32x4 av = *(const f32x4*)&stats[128 + j4];
    f32x4 cv = *(const f32x4*)&stats[192 + j4];
    f32x4 xo;
    ushort4v bo;
    #pragma unroll
    for (int i = 0; i < 4; ++i) {
        float r = fmaxf(fmaf(hv[i], av[i], cv[i]), 0.f);
        float xn = (xv[i] + r) * 0.5f;
        xo[i] = xn;
        bo[i] = f2bf(xn);
    }
    *(f32x4*)&x[(size_t)idx * 4] = xo;
    *(ushort4v*)&xb[(size_t)idx * 4] = bo;
}

// ======================= edge MLP (+ next-layer msg when NEXT) ==============
// R15: paired-tile interleave. Two independent chains (A=tile 2p, B=tile 2p+1)
// with disjoint LDS bounce buffers; weight fragments loaded once, used twice.
// w2 moved back to LDS to free 32 VGPR for the doubled fragment state.
template<int NEXT>
__global__ __launch_bounds__(256) void k_emlp_fused(
    const ushort* __restrict__ xb, ushort* __restrict__ eb,
    const int* __restrict__ src, const int* __restrict__ dst,
    const ushort* __restrict__ w1s, const float* __restrict__ b1,
    const ushort* __restrict__ w2s, const float* __restrict__ b2,
    const ushort* __restrict__ wm, const float* __restrict__ lbn,
    ushort* __restrict__ msgbuf)
{
    __shared__ ushort w1l[192 * 64];
    __shared__ ushort w2l[64 * 64];
    __shared__ ushort wml[NEXT ? 128 * 64 : 8];
    __shared__ ushort hb[4][2304];   // per-wave: hlA (1152) + hlB (1152)
    int tid = threadIdx.x;
    #pragma unroll
    for (int i = 0; i < 6; ++i)
        *(short8*)&w1l[(i * 256 + tid) * 8] = *(const short8*)&w1s[(i * 256 + tid) * 8];
    #pragma unroll
    for (int i = 0; i < 2; ++i)
        *(short8*)&w2l[(i * 256 + tid) * 8] = *(const short8*)&w2s[(i * 256 + tid) * 8];
    if (NEXT) {
        #pragma unroll
        for (int i = 0; i < 4; ++i)
            *(short8*)&wml[(i * 256 + tid) * 8] = *(const short8*)&wm[(i * 256 + tid) * 8];
    }
    __syncthreads();

    int wid = tid >> 6, lane = tid & 63;
    int c = lane & 15, kg = lane >> 4;

    float b1v[4], b2v[4], lbv[4];
    #pragma unroll
    for (int nt = 0; nt < 4; ++nt) {
        b1v[nt] = b1[nt * 16 + c];
        b2v[nt] = b2[nt * 16 + c];
        lbv[nt] = NEXT ? lbn[nt * 16 + c] : 0.f;
    }
    ushort* hlA = hb[wid];
    ushort* hlB = hb[wid] + 1152;

    int ebase = blockIdx.x * 256 + wid * 64;

    // ---- prologue: load pair-0 fragments (tiles 0 and 1) ----
    short8 aA[6], aB[6];
    {
        int mA = ebase + c, mB = ebase + 16 + c;
        int sA = src[mA], dA = dst[mA];
        int sB = src[mB], dB = dst[mB];
        const ushort* xsA = xb + (size_t)sA * 64;
        const ushort* xdA = xb + (size_t)dA * 64;
        const ushort* eeA = eb + (size_t)mA * 64;
        const ushort* xsB = xb + (size_t)sB * 64;
        const ushort* xdB = xb + (size_t)dB * 64;
        const ushort* eeB = eb + (size_t)mB * 64;
        aA[0] = *(const short8*)(xsA + kg * 8);
        aA[1] = *(const short8*)(xsA + 32 + kg * 8);
        aA[2] = *(const short8*)(xdA + kg * 8);
        aA[3] = *(const short8*)(xdA + 32 + kg * 8);
        aA[4] = *(const short8*)(eeA + kg * 8);
        aA[5] = *(const short8*)(eeA + 32 + kg * 8);
        aB[0] = *(const short8*)(xsB + kg * 8);
        aB[1] = *(const short8*)(xsB + 32 + kg * 8);
        aB[2] = *(const short8*)(xdB + kg * 8);
        aB[3] = *(const short8*)(xdB + 32 + kg * 8);
        aB[4] = *(const short8*)(eeB + kg * 8);
        aB[5] = *(const short8*)(eeB + 32 + kg * 8);
    }

    #pragma unroll 1
    for (int pr = 0; pr < 2; ++pr) {
        int e0A = ebase + pr * 32;
        int e0B = e0A + 16;
        int mA = e0A + c, mB = e0B + c;

        // GEMM1 A||B (shared weight fragment loads)
        f32x4 accA[4], accB[4];
        #pragma unroll
        for (int nt = 0; nt < 4; ++nt) {
            accA[nt] = f32x4{b1v[nt], b1v[nt], b1v[nt], b1v[nt]};
            accB[nt] = f32x4{b1v[nt], b1v[nt], b1v[nt], b1v[nt]};
        }
        #pragma unroll
        for (int ks = 0; ks < 6; ++ks) {
            #pragma unroll
            for (int nt = 0; nt < 4; ++nt) {
                short8 bf = *(const short8*)&w1l[((ks * 4 + kg) * 64 + nt * 16 + c) * 8];
                accA[nt] = __builtin_amdgcn_mfma_f32_16x16x32_bf16(aA[ks], bf, accA[nt], 0, 0, 0);
                accB[nt] = __builtin_amdgcn_mfma_f32_16x16x32_bf16(aB[ks], bf, accB[nt], 0, 0, 0);
            }
        }

        // prefetch next pair's fragments (latency hides under remaining phases)
        short8 nA[6], nB[6];
        if (pr == 0) {
            int pA = mA + 32, pB = mB + 32;
            int sA = src[pA], dA = dst[pA];
            int sB = src[pB], dB = dst[pB];
            const ushort* xsA = xb + (size_t)sA * 64;
            const ushort* xdA = xb + (size_t)dA * 64;
            const ushort* eeA = eb + (size_t)pA * 64;
            const ushort* xsB = xb + (size_t)sB * 64;
            const ushort* xdB = xb + (size_t)dB * 64;
            const ushort* eeB = eb + (size_t)pB * 64;
            nA[0] = *(const short8*)(xsA + kg * 8);
            nA[1] = *(const short8*)(xsA + 32 + kg * 8);
            nA[2] = *(const short8*)(xdA + kg * 8);
            nA[3] = *(const short8*)(xdA + 32 + kg * 8);
            nA[4] = *(const short8*)(eeA + kg * 8);
            nA[5] = *(const short8*)(eeA + 32 + kg * 8);
            nB[0] = *(const short8*)(xsB + kg * 8);
            nB[1] = *(const short8*)(xsB + 32 + kg * 8);
            nB[2] = *(const short8*)(xdB + kg * 8);
            nB[3] = *(const short8*)(xdB + 32 + kg * 8);
            nB[4] = *(const short8*)(eeB + kg * 8);
            nB[5] = *(const short8*)(eeB + 32 + kg * 8);
        }

        // h1 stores (A and B to disjoint buffers)
        #pragma unroll
        for (int nt = 0; nt < 4; ++nt) {
            #pragma unroll
            for (int i = 0; i < 4; ++i) {
                int rr = kg * 4 + i, cc = nt * 16 + c;
                int off = ((cc >> 3) * 16 + rr) * 8 + (cc & 7);
                hlA[off] = f2bf(fmaxf(accA[nt][i], 0.f));
                hlB[off] = f2bf(fmaxf(accB[nt][i], 0.f));
            }
        }
        // GEMM2 A||B (w2 fragments from LDS, shared)
        f32x4 a2A[4], a2B[4];
        #pragma unroll
        for (int nt = 0; nt < 4; ++nt) {
            a2A[nt] = f32x4{b2v[nt], b2v[nt], b2v[nt], b2v[nt]};
            a2B[nt] = f32x4{b2v[nt], b2v[nt], b2v[nt], b2v[nt]};
        }
        #pragma unroll
        for (int ks = 0; ks < 2; ++ks) {
            short8 haA = *(const short8*)&hlA[((ks * 4 + kg) * 16 + c) * 8];
            short8 haB = *(const short8*)&hlB[((ks * 4 + kg) * 16 + c) * 8];
            #pragma unroll
            for (int nt = 0; nt < 4; ++nt) {
                short8 bw = *(const short8*)&w2l[((ks * 4 + kg) * 64 + nt * 16 + c) * 8];
                a2A[nt] = __builtin_amdgcn_mfma_f32_16x16x32_bf16(haA, bw, a2A[nt], 0, 0, 0);
                a2B[nt] = __builtin_amdgcn_mfma_f32_16x16x32_bf16(haB, bw, a2B[nt], 0, 0, 0);
            }
        }
        // bounce updates -> A-layout (disjoint buffers)
        #pragma unroll
        for (int nt = 0; nt < 4; ++nt) {
            #pragma unroll
            for (int i = 0; i < 4; ++i) {
                int off = (kg * 4 + i) * 72 + nt * 16 + c;
                hlA[off] = f2bf(a2A[nt][i]);
                hlB[off] = f2bf(a2B[nt][i]);
            }
        }
        short8 u0A = *(const short8*)&hlA[c * 72 + kg * 8];
        short8 u1A = *(const short8*)&hlA[c * 72 + 32 + kg * 8];
        short8 u0B = *(const short8*)&hlB[c * 72 + kg * 8];
        short8 u1B = *(const short8*)&hlB[c * 72 + 32 + kg * 8];
        short8 enA0, enA1, enB0, enB1;
        #pragma unroll
        for (int j = 0; j < 8; ++j) {
            enA0[j] = (short)f2bf(bf2f((ushort)aA[4][j]) + 0.5f * bf2f((ushort)u0A[j]));
            enA1[j] = (short)f2bf(bf2f((ushort)aA[5][j]) + 0.5f * bf2f((ushort)u1A[j]));
            enB0[j] = (short)f2bf(bf2f((ushort)aB[4][j]) + 0.5f * bf2f((ushort)u0B[j]));
            enB1[j] = (short)f2bf(bf2f((ushort)aB[5][j]) + 0.5f * bf2f((ushort)u1B[j]));
        }
        *(short8*)&eb[(size_t)mA * 64 + kg * 8]      = enA0;
        *(short8*)&eb[(size_t)mA * 64 + 32 + kg * 8] = enA1;
        *(short8*)&eb[(size_t)mB * 64 + kg * 8]      = enB0;
        *(short8*)&eb[(size_t)mB * 64 + 32 + kg * 8] = enB1;

        if (NEXT) {
            // msg GEMMs A||B (wml fragments shared)
            f32x4 a3A[4], a3B[4];
            #pragma unroll
            for (int nt = 0; nt < 4; ++nt) {
                a3A[nt] = f32x4{lbv[nt], lbv[nt], lbv[nt], lbv[nt]};
                a3B[nt] = f32x4{lbv[nt], lbv[nt], lbv[nt], lbv[nt]};
            }
            short8 afA[4] = {aA[0], aA[1], enA0, enA1};
            short8 afB[4] = {aB[0], aB[1], enB0, enB1};
            #pragma unroll
            for (int ks = 0; ks < 4; ++ks) {
                #pragma unroll
                for (int nt = 0; nt < 4; ++nt) {
                    short8 bf = *(const short8*)&wml[((ks * 4 + kg) * 64 + nt * 16 + c) * 8];
                    a3A[nt] = __builtin_amdgcn_mfma_f32_16x16x32_bf16(afA[ks], bf, a3A[nt], 0, 0, 0);
                    a3B[nt] = __builtin_amdgcn_mfma_f32_16x16x32_bf16(afB[ks], bf, a3B[nt], 0, 0, 0);
                }
            }
            #pragma unroll
            for (int nt = 0; nt < 4; ++nt) {
                #pragma unroll
                for (int i = 0; i < 4; ++i) {
                    int off = (kg * 4 + i) * 72 + nt * 16 + c;
                    hlA[off] = f2bf(fmaxf(a3A[nt][i], 0.f));
                    hlB[off] = f2bf(fmaxf(a3B[nt][i], 0.f));
                }
            }
            // coalesced msgbuf stores (edge order), A then B
            #pragma unroll
            for (int r = 0; r < 2; ++r) {
                int q = r * 64 + lane;
                *(short8*)&msgbuf[(size_t)(e0A + (q >> 3)) * 64 + (q & 7) * 8] =
                    *(short8*)&hlA[(q >> 3) * 72 + (q & 7) * 8];
                *(short8*)&msgbuf[(size_t)(e0B + (q >> 3)) * 64 + (q & 7) * 8] =
                    *(short8*)&hlB[(q >> 3) * 72 + (q & 7) * 8];
            }
        }

        // rotate pipeline
        if (pr == 0) {
            #pragma unroll
            for (int i = 0; i < 6; ++i) { aA[i] = nA[i]; aB[i] = nB[i]; }
        }
    }
}

// ======================= readout (pipelined fragment prefetch) ==============
__global__ __launch_bounds__(256) void k_readout_mfma(
    const ushort* __restrict__ xb, const ushort* __restrict__ eb,
    const int* __restrict__ src, const int* __restrict__ dst,
    const ushort* __restrict__ w1s, const float* __restrict__ b1,
    const float* __restrict__ w2, const float* __restrict__ b2,
    const float* __restrict__ w3, const float* __restrict__ b3,
    float* __restrict__ logit)
{
    __shared__ ushort w1l[192 * 64];
    __shared__ ushort hw[4][64 * 50];
    int tid = threadIdx.x;
    #pragma unroll
    for (int i = 0; i < 6; ++i)
        *(short8*)&w1l[(i * 256 + tid) * 8] = *(const short8*)&w1s[(i * 256 + tid) * 8];
    __syncthreads();

    int wid = tid >> 6, lane = tid & 63;
    int c = lane & 15, kg = lane >> 4;
    float b1v[4];
    #pragma unroll
    for (int nt = 0; nt < 4; ++nt) b1v[nt] = (nt * 16 + c < 50) ? b1[nt * 16 + c] : 0.f;

    int ebase = blockIdx.x * 256 + wid * 64;

    // prologue: tile-0 fragments (raw; brelu applied at consumption)
    short8 a[6];
    {
        int myedge = ebase + c;
        int s = src[myedge], d = dst[myedge];
        const ushort* xs = xb + (size_t)s * 64;
        const ushort* xd = xb + (size_t)d * 64;
        const ushort* ee = eb + (size_t)myedge * 64;
        a[0] = *(const short8*)(xs + kg * 8);
        a[1] = *(const short8*)(xs + 32 + kg * 8);
        a[2] = *(const short8*)(xd + kg * 8);
        a[3] = *(const short8*)(xd + 32 + kg * 8);
        a[4] = *(const short8*)(ee + kg * 8);
        a[5] = *(const short8*)(ee + 32 + kg * 8);
    }

    #pragma unroll 1
    for (int t4 = 0; t4 < 4; ++t4) {
        int e0 = ebase + t4 * 16;
        int myedge = e0 + c;

        short8 an[6];
        if (t4 < 3) {
            int sn = src[myedge + 16];
            int dn = dst[myedge + 16];
            const ushort* xsn = xb + (size_t)sn * 64;
            const ushort* xdn = xb + (size_t)dn * 64;
            const ushort* een = eb + (size_t)(myedge + 16) * 64;
            an[0] = *(const short8*)(xsn + kg * 8);
            an[1] = *(const short8*)(xsn + 32 + kg * 8);
            an[2] = *(const short8*)(xdn + kg * 8);
            an[3] = *(const short8*)(xdn + 32 + kg * 8);
            an[4] = *(const short8*)(een + kg * 8);
            an[5] = *(const short8*)(een + 32 + kg * 8);
        }

        short8 af[6];
        af[0] = brelu(a[0]); af[1] = brelu(a[1]);
        af[2] = brelu(a[2]); af[3] = brelu(a[3]);
        af[4] = a[4];        af[5] = a[5];

        f32x4 acc[4];
        #pragma unroll
        for (int nt = 0; nt < 4; ++nt) acc[nt] = f32x4{b1v[nt], b1v[nt], b1v[nt], b1v[nt]};
        #pragma unroll
        for (int ks = 0; ks < 6; ++ks) {
            #pragma unroll
            for (int nt = 0; nt < 4; ++nt) {
                short8 bf = *(const short8*)&w1l[((ks * 4 + kg) * 64 + nt * 16 + c) * 8];
                acc[nt] = __builtin_amdgcn_mfma_f32_16x16x32_bf16(af[ks], bf, acc[nt], 0, 0, 0);
            }
        }
        #pragma unroll
        for (int nt = 0; nt < 4; ++nt) {
            #pragma unroll
            for (int i = 0; i < 4; ++i) {
                int rr = kg * 4 + i, cc = nt * 16 + c;
                if (cc < 50)
                    hw[wid][(t4 * 16 + rr) * 50 + cc] = f2bf(fmaxf(acc[nt][i], 0.f));
            }
        }
        if (t4 < 3) {
            #pragma unroll
            for (int i = 0; i < 6; ++i) a[i] = an[i];
        }
    }
    int edge = blockIdx.x * 256 + wid * 64 + lane;
    const ushort* hrow = &hw[wid][lane * 50];
    float a25[25];
    #pragma unroll
    for (int j = 0; j < 25; ++j) a25[j] = b2[j];
    #pragma unroll 2
    for (int k = 0; k < 50; ++k) {
        float hv = bf2f(hrow[k]);
        #pragma unroll
        for (int j = 0; j < 25; ++j) a25[j] = fmaf(hv, w2[k * 25 + j], a25[j]);
    }
    float lg = b3[0];
    #pragma unroll
    for (int k = 0; k < 25; ++k) lg = fmaf(fmaxf(a25[k], 0.f), w3[k], lg);
    logit[edge] = lg;
}

// ---------------------------------------------------------------------------
extern "C" void kernel_launch(void* const* d_in, const int* in_sizes, int n_in,
                              void* d_out, int out_size, void* d_ws, size_t ws_size,
                              hipStream_t stream)
{
    const float* x_in  = (const float*)d_in[0];
    const float* eattr = (const float*)d_in[1];
    const int*   src   = (const int*)d_in[2];
    const int*   dst   = (const int*)d_in[3];
    const float* n_w   = (const float*)d_in[4];
    const float* n_b   = (const float*)d_in[5];
    const float* e_w   = (const float*)d_in[6];
    const float* e_b   = (const float*)d_in[7];
    const float* lw    = (const float*)d_in[8];
    const float* lb    = (const float*)d_in[9];
    const float* cw1   = (const float*)d_in[10];
    const float* cb1   = (const float*)d_in[11];
    const float* cw2   = (const float*)d_in[12];
    const float* cb2   = (const float*)d_in[13];
    const float* ew1   = (const float*)d_in[14];
    const float* eb1   = (const float*)d_in[15];
    const float* ew2   = (const float*)d_in[16];
    const float* eb2   = (const float*)d_in[17];
    const float* gam   = (const float*)d_in[18];
    const float* bet   = (const float*)d_in[19];
    const float* m1w   = (const float*)d_in[20];
    const float* m1b   = (const float*)d_in[21];
    const float* m2w   = (const float*)d_in[22];
    const float* m2b   = (const float*)d_in[23];
    const float* m3w   = (const float*)d_in[24];
    const float* m3b   = (const float*)d_in[25];

    float* xbuf  = (float*)d_out;                  // [NN,64] f32 master (output 0)
    float* logit = xbuf + (size_t)NN * 64;         // [NE]

    ushort* eb     = (ushort*)d_ws;                   // [NE,64]
    float*  tmp    = (float*)(eb + (size_t)NE * 64);  // [NN,64] h
    float*  stats  = tmp + (size_t)NN * 64;           // 512 (2 layers x 256)
    ushort* w1s    = (ushort*)(stats + 512);          // 2*192*64
    ushort* w2s    = w1s + 2 * 192 * 64;              // 2*64*64
    ushort* m1s    = w2s + 2 * 64 * 64;               // 192*64
    ushort* xb     = m1s + 192 * 64;                  // [NN,64]
    ushort* wms    = xb + (size_t)NN * 64;            // 2*128*64
    ushort* cw1s   = wms + 2 * 128 * 64;              // 2*64*64
    ushort* cw2s   = cw1s + 2 * 64 * 64;              // 2*64*64
    ushort* nws    = cw2s + 2 * 64 * 64;              // 32*64
    ushort* ews    = nws + 32 * 64;                   // 32*64
    ushort* msgbuf = ews + 32 * 64;                   // [NE,64] (EDGE order)
    int*    hist   = (int*)(msgbuf + (size_t)NE * 64);// NN
    int*    rp     = hist + NN;                       // NN+1
    int*    cursor = rp + NN + 1;                     // NN
    int*    parts  = cursor + NN;                     // 128
    int*    eidx   = parts + 128;                     // NE

    // ---- CSR build (once; reused by both layers) ----
    hipMemsetAsync(hist, 0, NN * sizeof(int), stream);
    hipMemsetAsync(stats, 0, 512 * sizeof(float), stream);
    k_hist<<<NE / 256, 256, 0, stream>>>(dst, hist);
    k_scan_part<<<NB_SCAN, 256, 0, stream>>>(hist, rp, parts);
    k_scan_tops<<<1, 128, 0, stream>>>(parts, rp);
    k_scan_add<<<(NN + 255) / 256, 256, 0, stream>>>(rp, parts, cursor);
    k_scatter<<<NE / 256, 256, 0, stream>>>(dst, cursor, eidx);

    // ---- weight prep ----
    k_w_subtile<<<48, 256, 0, stream>>>(ew1,            w1s,            192, 64);
    k_w_subtile<<<48, 256, 0, stream>>>(ew1 + 192 * 64, w1s + 192 * 64, 192, 64);
    k_w_subtile<<<16, 256, 0, stream>>>(ew2,            w2s,            64, 64);
    k_w_subtile<<<16, 256, 0, stream>>>(ew2 + 64 * 64,  w2s + 64 * 64,  64, 64);
    k_w_subtile<<<48, 256, 0, stream>>>(m1w,            m1s,            192, 50);
    k_w_msg<<<32, 256, 0, stream>>>(lw,           wms);
    k_w_msg<<<32, 256, 0, stream>>>(lw + 64 * 64, wms + 128 * 64);
    k_w_subtile<<<16, 256, 0, stream>>>(cw1,            cw1s,           64, 64);
    k_w_subtile<<<16, 256, 0, stream>>>(cw1 + 64 * 64,  cw1s + 64 * 64, 64, 64);
    k_w_subtile<<<16, 256, 0, stream>>>(cw2,            cw2s,           64, 64);
    k_w_subtile<<<16, 256, 0, stream>>>(cw2 + 64 * 64,  cw2s + 64 * 64, 64, 64);
    k_w_padk<<<8, 256, 0, stream>>>(n_w, nws, 32, 32);
    k_w_padk<<<8, 256, 0, stream>>>(e_w, ews, 16, 32);

    k_node_emb_mfma<<<(NN / 16 + 3) / 4, 256, 0, stream>>>(x_in, nws, n_b, xbuf, xb);
    // e0 + msg for layer 0 (edge-order msg store)
    k_edge_emb_fused<<<NE / 64, 256, 0, stream>>>(eattr, ews, e_b, eb,
                                                  xb, src, wms, lb, msgbuf);

    for (int l = 0; l < 2; ++l) {
        float* st = stats + l * 256;
        k_conv_csr<<<(NN / 16 + 3) / 4, 256, 0, stream>>>(
            xbuf, msgbuf, rp, eidx, tmp, cw1s + l * 64 * 64, cb1 + l * 64,
            cw2s + l * 64 * 64, cb2 + l * 64, st);
        k_bnfin<<<1, 64, 0, stream>>>(st, gam + l * 64, bet + l * 64);
        k_xupd4<<<NN * 16 / 256, 256, 0, stream>>>(xbuf, tmp, st, xb);
        if (l == 0) {
            k_emlp_fused<1><<<NE / 256, 256, 0, stream>>>(
                xb, eb, src, dst, w1s, eb1, w2s, eb2,
                wms + 128 * 64, lb + 64, msgbuf);
        } else {
            k_emlp_fused<0><<<NE / 256, 256, 0, stream>>>(
                xb, eb, src, dst, w1s + 192 * 64, eb1 + 64, w2s + 64 * 64, eb2 + 64,
                wms, lb, msgbuf);
        }
    }

    k_readout_mfma<<<NE / 256, 256, 0, stream>>>(xb, eb, src, dst,
                                                 m1s, m1b, m2w, m2b, m3w, m3b, logit);
}

// Round 16
// 536.653 us; speedup vs baseline: 1.0483x; 1.0483x over previous
//
#include <hip/hip_runtime.h>

#define NN 100000
#define NE 640000
#define NB_SCAN 98   // ceil(NN/1024)

typedef __attribute__((ext_vector_type(8))) short short8;
typedef __attribute__((ext_vector_type(4))) float f32x4;
typedef __attribute__((ext_vector_type(4))) ushort ushort4v;

__device__ __forceinline__ float bf2f(ushort u) {
    unsigned v = ((unsigned)u) << 16;
    return __builtin_bit_cast(float, v);
}
__device__ __forceinline__ ushort f2bf(float f) {
    unsigned u = __builtin_bit_cast(unsigned, f);
    u += 0x7fffu + ((u >> 16) & 1u);   // RNE
    return (ushort)(u >> 16);
}
__device__ __forceinline__ short8 brelu(short8 v) {
    #pragma unroll
    for (int i = 0; i < 8; ++i) v[i] = (v[i] < (short)0) ? (short)0 : v[i];
    return v;
}

// ======================= CSR build (topology, once per call) ================
__global__ void k_hist(const int* __restrict__ dst, int* __restrict__ hist)
{
    int i = blockIdx.x * 256 + threadIdx.x;   // NE threads
    atomicAdd(&hist[dst[i]], 1);
}

__global__ __launch_bounds__(256) void k_scan_part(const int* __restrict__ hist,
                                                   int* __restrict__ rp,
                                                   int* __restrict__ parts)
{
    __shared__ int s[256];
    int b = blockIdx.x, t = threadIdx.x;
    int base = b * 1024 + t * 4;
    int v[4]; int sum = 0;
    #pragma unroll
    for (int i = 0; i < 4; ++i) { int idx = base + i; v[i] = (idx < NN) ? hist[idx] : 0; sum += v[i]; }
    s[t] = sum; __syncthreads();
    for (int off = 1; off < 256; off <<= 1) {
        int x = (t >= off) ? s[t - off] : 0;
        __syncthreads(); s[t] += x; __syncthreads();
    }
    int excl = s[t] - sum;
    if (t == 255) parts[b] = s[255];
    int run = excl;
    #pragma unroll
    for (int i = 0; i < 4; ++i) { int idx = base + i; if (idx < NN) rp[idx] = run; run += v[i]; }
}

__global__ void k_scan_tops(int* __restrict__ parts, int* __restrict__ rp)
{
    __shared__ int s[128];
    int t = threadIdx.x;   // 128 threads
    int v = (t < NB_SCAN) ? parts[t] : 0;
    s[t] = v; __syncthreads();
    for (int off = 1; off < 128; off <<= 1) {
        int x = (t >= off) ? s[t - off] : 0;
        __syncthreads(); s[t] += x; __syncthreads();
    }
    parts[t] = s[t] - v;   // exclusive
    if (t == 0) rp[NN] = NE;
}

__global__ __launch_bounds__(256) void k_scan_add(int* __restrict__ rp,
                                                  const int* __restrict__ parts,
                                                  int* __restrict__ cursor)
{
    int i = blockIdx.x * 256 + threadIdx.x;
    if (i >= NN) return;
    int v = rp[i] + parts[i >> 10];
    rp[i] = v; cursor[i] = v;
}

// eidx[p] = edge id at dst-sorted position p
__global__ void k_scatter(const int* __restrict__ dst,
                          int* __restrict__ cursor, int* __restrict__ eidx)
{
    int i = blockIdx.x * 256 + threadIdx.x;   // NE threads
    int d = dst[i];
    int p = atomicAdd(&cursor[d], 1);
    eidx[p] = i;
}

// ======================= weight prep =======================================
__global__ void k_w_subtile(const float* __restrict__ w, ushort* __restrict__ out,
                            int K, int Nin)
{
    int t = blockIdx.x * 256 + threadIdx.x;
    if (t >= K * 64) return;
    int k = t >> 6, c = t & 63;
    float v = (c < Nin) ? w[k * Nin + c] : 0.f;
    out[((k >> 3) * 64 + c) * 8 + (k & 7)] = f2bf(v);
}

__global__ void k_w_padk(const float* __restrict__ w, ushort* __restrict__ out,
                         int Kreal, int Kpad)
{
    int t = blockIdx.x * 256 + threadIdx.x;
    if (t >= Kpad * 64) return;
    int k = t >> 6, c = t & 63;
    float v = (k < Kreal) ? w[k * 64 + c] : 0.f;
    out[((k >> 3) * 64 + c) * 8 + (k & 7)] = f2bf(v);
}

__global__ void k_w_msg(const float* __restrict__ lw, ushort* __restrict__ out)
{
    int t = blockIdx.x * 256 + threadIdx.x;   // 128*64
    if (t >= 128 * 64) return;
    int k = t >> 6, c = t & 63;
    float v = (k < 64) ? (k == c ? 1.f : 0.f) : lw[(k - 64) * 64 + c];
    out[((k >> 3) * 64 + c) * 8 + (k & 7)] = f2bf(v);
}

// ======================= node embedding ====================================
__global__ __launch_bounds__(256) void k_node_emb_mfma(
    const float* __restrict__ xin, const ushort* __restrict__ ws,
    const float* __restrict__ b, float* __restrict__ xout,
    ushort* __restrict__ xb)
{
    __shared__ ushort wl[32 * 64];
    __shared__ float fbuf[4][16 * 64];
    __shared__ ushort bbuf[4][16 * 64];
    int tid = threadIdx.x;
    *(short8*)&wl[tid * 8] = *(const short8*)&ws[tid * 8];
    __syncthreads();

    int wid = tid >> 6, lane = tid & 63, c = lane & 15, kg = lane >> 4;
    int t = blockIdx.x * 4 + wid;
    if (t >= NN / 16) return;
    int n0 = t * 16;

    const float* xr = xin + (size_t)(n0 + c) * 32 + kg * 8;
    f32x4 u0 = *(const f32x4*)xr, u1 = *(const f32x4*)(xr + 4);
    short8 a;
    #pragma unroll
    for (int j = 0; j < 4; ++j) { a[j] = (short)f2bf(u0[j]); a[4 + j] = (short)f2bf(u1[j]); }

    f32x4 acc[4];
    #pragma unroll
    for (int nt = 0; nt < 4; ++nt) {
        float bv = b[nt * 16 + c];
        acc[nt] = f32x4{bv, bv, bv, bv};
        short8 bf = *(const short8*)&wl[(kg * 64 + nt * 16 + c) * 8];
        acc[nt] = __builtin_amdgcn_mfma_f32_16x16x32_bf16(a, bf, acc[nt], 0, 0, 0);
    }
    #pragma unroll
    for (int nt = 0; nt < 4; ++nt)
        #pragma unroll
        for (int i = 0; i < 4; ++i) {
            int rr = kg * 4 + i, cc = nt * 16 + c;
            float v = acc[nt][i];
            fbuf[wid][rr * 64 + cc] = v;
            bbuf[wid][rr * 64 + cc] = f2bf(v);
        }
    #pragma unroll
    for (int r = 0; r < 4; ++r) {
        int q = r * 64 + lane;
        *(f32x4*)&xout[(size_t)(n0 + (q >> 4)) * 64 + (q & 15) * 4] =
            *(f32x4*)&fbuf[wid][q * 4];
    }
    #pragma unroll
    for (int r = 0; r < 2; ++r) {
        int q = r * 64 + lane;
        *(short8*)&xb[(size_t)(n0 + (q >> 3)) * 64 + (q & 7) * 8] =
            *(short8*)&bbuf[wid][q * 8];
    }
}

// ======================= edge embedding + layer-0 msg (fused) ==============
// e0 = eattr @ ew + eb;  msg0 = relu([x0[src] | e0] @ wms0 + lb0)
// msgbuf stored in EDGE order (coalesced); conv gathers via eidx.
__global__ __launch_bounds__(256) void k_edge_emb_fused(
    const float* __restrict__ ein, const ushort* __restrict__ ws,
    const float* __restrict__ b, ushort* __restrict__ eb,
    const ushort* __restrict__ xb, const int* __restrict__ src,
    const ushort* __restrict__ wm, const float* __restrict__ lb,
    ushort* __restrict__ msgbuf)
{
    __shared__ ushort wl[32 * 64];
    __shared__ ushort wml[128 * 64];
    __shared__ ushort bbuf[4][16 * 72];   // padded rows (72) for b128 readback
    int tid = threadIdx.x;
    *(short8*)&wl[tid * 8] = *(const short8*)&ws[tid * 8];
    #pragma unroll
    for (int i = 0; i < 4; ++i)
        *(short8*)&wml[(i * 256 + tid) * 8] = *(const short8*)&wm[(i * 256 + tid) * 8];
    __syncthreads();

    int wid = tid >> 6, lane = tid & 63, c = lane & 15, kg = lane >> 4;
    int e0 = (blockIdx.x * 4 + wid) * 16;
    ushort* bb = bbuf[wid];

    // prefetch x[src] early (random gather overlaps the e0 GEMM)
    const ushort* xs = xb + (size_t)src[e0 + c] * 64;
    short8 a0 = *(const short8*)(xs + kg * 8);
    short8 a1 = *(const short8*)(xs + 32 + kg * 8);

    // ---- e0 = emb(edge_attr), K padded 16->32 ----
    short8 a = (short8)0;
    if (kg < 2) {
        const float* er = ein + (size_t)(e0 + c) * 16 + kg * 8;
        f32x4 u0 = *(const f32x4*)er, u1 = *(const f32x4*)(er + 4);
        #pragma unroll
        for (int j = 0; j < 4; ++j) { a[j] = (short)f2bf(u0[j]); a[4 + j] = (short)f2bf(u1[j]); }
    }
    f32x4 acc[4];
    #pragma unroll
    for (int nt = 0; nt < 4; ++nt) {
        float bv = b[nt * 16 + c];
        acc[nt] = f32x4{bv, bv, bv, bv};
        short8 bf = *(const short8*)&wl[(kg * 64 + nt * 16 + c) * 8];
        acc[nt] = __builtin_amdgcn_mfma_f32_16x16x32_bf16(a, bf, acc[nt], 0, 0, 0);
    }
    #pragma unroll
    for (int nt = 0; nt < 4; ++nt)
        #pragma unroll
        for (int i = 0; i < 4; ++i)
            bb[(kg * 4 + i) * 72 + nt * 16 + c] = f2bf(acc[nt][i]);
    // coalesced eb store
    #pragma unroll
    for (int r = 0; r < 2; ++r) {
        int q = r * 64 + lane;
        *(short8*)&eb[(size_t)(e0 + (q >> 3)) * 64 + (q & 7) * 8] =
            *(short8*)&bb[(q >> 3) * 72 + (q & 7) * 8];
    }
    // ---- msg0 = relu([x|e0] @ wms + lb) ----
    short8 en0 = *(const short8*)&bb[c * 72 + kg * 8];
    short8 en1 = *(const short8*)&bb[c * 72 + 32 + kg * 8];

    f32x4 acc3[4];
    #pragma unroll
    for (int nt = 0; nt < 4; ++nt) {
        float bv = lb[nt * 16 + c];
        acc3[nt] = f32x4{bv, bv, bv, bv};
    }
    short8 af[4] = {a0, a1, en0, en1};
    #pragma unroll
    for (int ks = 0; ks < 4; ++ks) {
        #pragma unroll
        for (int nt = 0; nt < 4; ++nt) {
            short8 bf = *(const short8*)&wml[((ks * 4 + kg) * 64 + nt * 16 + c) * 8];
            acc3[nt] = __builtin_amdgcn_mfma_f32_16x16x32_bf16(af[ks], bf, acc3[nt], 0, 0, 0);
        }
    }
    #pragma unroll
    for (int nt = 0; nt < 4; ++nt)
        #pragma unroll
        for (int i = 0; i < 4; ++i)
            bb[(kg * 4 + i) * 72 + nt * 16 + c] = f2bf(fmaxf(acc3[nt][i], 0.f));
    // coalesced msgbuf store (edge order)
    #pragma unroll
    for (int r = 0; r < 2; ++r) {
        int q = r * 64 + lane;
        *(short8*)&msgbuf[(size_t)(e0 + (q >> 3)) * 64 + (q & 7) * 8] =
            *(short8*)&bb[(q >> 3) * 72 + (q & 7) * 8];
    }
}

// ======================= conv with CSR aggregation (gather msg rows) ========
// software-pipelined gather loop (prefetch row j+1 while accumulating j)
__global__ __launch_bounds__(256) void k_conv_csr(
    const float* __restrict__ x, const ushort* __restrict__ msgbuf,
    const int* __restrict__ rp, const int* __restrict__ eidx,
    float* __restrict__ hout,
    const ushort* __restrict__ w1s, const float* __restrict__ b1,
    const ushort* __restrict__ w2s, const float* __restrict__ b2,
    float* __restrict__ stats)
{
    __shared__ ushort w1l[64 * 64];
    __shared__ ushort w2l[64 * 64];
    __shared__ ushort h1l[4][1024];
    __shared__ float red[2][4][64];
    int tid = threadIdx.x;
    #pragma unroll
    for (int i = 0; i < 2; ++i) {
        *(short8*)&w1l[(i * 256 + tid) * 8] = *(const short8*)&w1s[(i * 256 + tid) * 8];
        *(short8*)&w2l[(i * 256 + tid) * 8] = *(const short8*)&w2s[(i * 256 + tid) * 8];
    }
    __syncthreads();

    int wid = tid >> 6, lane = tid & 63;
    int c = lane & 15, kg = lane >> 4;

    short8 w2f[2][4];
    #pragma unroll
    for (int ks = 0; ks < 2; ++ks)
        #pragma unroll
        for (int nt = 0; nt < 4; ++nt)
            w2f[ks][nt] = *(const short8*)&w2l[((ks * 4 + kg) * 64 + nt * 16 + c) * 8];

    float b1v[4], b2v[4];
    #pragma unroll
    for (int nt = 0; nt < 4; ++nt) { b1v[nt] = b1[nt * 16 + c]; b2v[nt] = b2[nt * 16 + c]; }

    float s1[4] = {0.f, 0.f, 0.f, 0.f}, s2[4] = {0.f, 0.f, 0.f, 0.f};
    ushort* hl = h1l[wid];

    int t = blockIdx.x * 4 + wid;
    if (t < NN / 16) {
        int n0 = t * 16;
        int n = n0 + c;
        int jb = rp[n], je = rp[n + 1];
        float sm0[8] = {0,0,0,0,0,0,0,0}, sm1[8] = {0,0,0,0,0,0,0,0};
        if (jb < je) {
            int row = eidx[jb];
            short8 m0 = *(const short8*)&msgbuf[(size_t)row * 64 + kg * 8];
            short8 m1 = *(const short8*)&msgbuf[(size_t)row * 64 + 32 + kg * 8];
            for (int j = jb + 1; j <= je; ++j) {
                short8 p0, p1;
                if (j < je) {
                    int nrow = eidx[j];
                    p0 = *(const short8*)&msgbuf[(size_t)nrow * 64 + kg * 8];
                    p1 = *(const short8*)&msgbuf[(size_t)nrow * 64 + 32 + kg * 8];
                }
                #pragma unroll
                for (int i = 0; i < 8; ++i) {
                    sm0[i] += bf2f((ushort)m0[i]);
                    sm1[i] += bf2f((ushort)m1[i]);
                }
                if (j < je) { m0 = p0; m1 = p1; }
            }
        }
        const float* xr = x + (size_t)n * 64;
        f32x4 u0 = *(const f32x4*)(xr + kg * 8);
        f32x4 u1 = *(const f32x4*)(xr + kg * 8 + 4);
        f32x4 v0 = *(const f32x4*)(xr + 32 + kg * 8);
        f32x4 v1 = *(const f32x4*)(xr + 32 + kg * 8 + 4);
        short8 a[2];
        #pragma unroll
        for (int j = 0; j < 4; ++j) {
            a[0][j]     = (short)f2bf(u0[j] + sm0[j]);
            a[0][4 + j] = (short)f2bf(u1[j] + sm0[4 + j]);
            a[1][j]     = (short)f2bf(v0[j] + sm1[j]);
            a[1][4 + j] = (short)f2bf(v1[j] + sm1[4 + j]);
        }
        f32x4 acc[4];
        #pragma unroll
        for (int nt = 0; nt < 4; ++nt) acc[nt] = f32x4{b1v[nt], b1v[nt], b1v[nt], b1v[nt]};
        #pragma unroll
        for (int ks = 0; ks < 2; ++ks) {
            #pragma unroll
            for (int nt = 0; nt < 4; ++nt) {
                short8 bf = *(const short8*)&w1l[((ks * 4 + kg) * 64 + nt * 16 + c) * 8];
                acc[nt] = __builtin_amdgcn_mfma_f32_16x16x32_bf16(a[ks], bf, acc[nt], 0, 0, 0);
            }
        }
        #pragma unroll
        for (int nt = 0; nt < 4; ++nt) {
            #pragma unroll
            for (int i = 0; i < 4; ++i) {
                int rr = kg * 4 + i, cc = nt * 16 + c;
                hl[((cc >> 3) * 16 + rr) * 8 + (cc & 7)] = f2bf(fmaxf(acc[nt][i], 0.f));
            }
        }
        f32x4 acc2[4];
        #pragma unroll
        for (int nt = 0; nt < 4; ++nt) acc2[nt] = f32x4{b2v[nt], b2v[nt], b2v[nt], b2v[nt]};
        #pragma unroll
        for (int ks = 0; ks < 2; ++ks) {
            short8 ha = *(const short8*)&hl[((ks * 4 + kg) * 16 + c) * 8];
            #pragma unroll
            for (int nt = 0; nt < 4; ++nt)
                acc2[nt] = __builtin_amdgcn_mfma_f32_16x16x32_bf16(ha, w2f[ks][nt], acc2[nt], 0, 0, 0);
        }
        #pragma unroll
        for (int nt = 0; nt < 4; ++nt) {
            #pragma unroll
            for (int i = 0; i < 4; ++i) {
                int rr = kg * 4 + i, cc = nt * 16 + c;
                float h2 = acc2[nt][i];
                hout[(size_t)(n0 + rr) * 64 + cc] = h2;
                s1[nt] += h2;
                s2[nt] += h2 * h2;
            }
        }
    }
    #pragma unroll
    for (int nt = 0; nt < 4; ++nt) {
        float v1 = s1[nt], v2 = s2[nt];
        v1 += __shfl_xor(v1, 16); v1 += __shfl_xor(v1, 32);
        v2 += __shfl_xor(v2, 16); v2 += __shfl_xor(v2, 32);
        s1[nt] = v1; s2[nt] = v2;
    }
    if (lane < 16) {
        #pragma unroll
        for (int nt = 0; nt < 4; ++nt) {
            red[0][wid][nt * 16 + c] = s1[nt];
            red[1][wid][nt * 16 + c] = s2[nt];
        }
    }
    __syncthreads();
    if (wid == 0) {
        float a = red[0][0][lane] + red[0][1][lane] + red[0][2][lane] + red[0][3][lane];
        float b = red[1][0][lane] + red[1][1][lane] + red[1][2][lane] + red[1][3][lane];
        unsafeAtomicAdd(&stats[lane], a);
        unsafeAtomicAdd(&stats[64 + lane], b);
    }
}

__global__ void k_bnfin(float* __restrict__ stats,
                        const float* __restrict__ gamma,
                        const float* __restrict__ beta)
{
    int j = threadIdx.x;
    float mu = stats[j] * (1.f / NN);
    float var = stats[64 + j] * (1.f / NN) - mu * mu;
    float a = gamma[j] * rsqrtf(var + 1e-5f);
    stats[128 + j] = a;
    stats[192 + j] = beta[j] - mu * a;
}

__global__ __launch_bounds__(256) void k_xupd4(float* __restrict__ x,
                                               const float* __restrict__ h,
                                               const float* __restrict__ stats,
                                               ushort* __restrict__ xb)
{
    int idx = blockIdx.x * 256 + threadIdx.x;   // NN*16 threads
    int j4 = (idx & 15) * 4;
    f32x4 hv = *(const f32x4*)&h[(size_t)idx * 4];
    f32x4 xv = *(const f32x4*)&x[(size_t)idx * 4];
    f32x4 av = *(const f32x4*)&stats[128 + j4];
    f32x4 cv = *(const f32x4*)&stats[192 + j4];
    f32x4 xo;
    ushort4v bo;
    #pragma unroll
    for (int i = 0; i < 4; ++i) {
        float r = fmaxf(fmaf(hv[i], av[i], cv[i]), 0.f);
        float xn = (xv[i] + r) * 0.5f;
        xo[i] = xn;
        bo[i] = f2bf(xn);
    }
    *(f32x4*)&x[(size_t)idx * 4] = xo;
    *(ushort4v*)&xb[(size_t)idx * 4] = bo;
}

// ======================= edge MLP (+ next-layer msg when NEXT) ==============
// e_new = e + 0.5*(relu(cat(x_s,x_d,e)@w1+b1)@w2+b2)
// if NEXT: msg_next = relu([x_s | e_new] @ wm + lbn) -> msgbuf[edge] (coalesced)
// 1-deep register pipeline: next tile's gathers issued at TOP of iteration.
template<int NEXT>
__global__ __launch_bounds__(256) void k_emlp_fused(
    const ushort* __restrict__ xb, ushort* __restrict__ eb,
    const int* __restrict__ src, const int* __restrict__ dst,
    const ushort* __restrict__ w1s, const float* __restrict__ b1,
    const ushort* __restrict__ w2s, const float* __restrict__ b2,
    const ushort* __restrict__ wm, const float* __restrict__ lbn,
    ushort* __restrict__ msgbuf)
{
    __shared__ ushort w1l[192 * 64];
    __shared__ ushort wml[NEXT ? 128 * 64 : 8];
    __shared__ ushort hb[4][1152];   // per-wave: h1 subtile / 72-padded bounce
    int tid = threadIdx.x;
    #pragma unroll
    for (int i = 0; i < 6; ++i)
        *(short8*)&w1l[(i * 256 + tid) * 8] = *(const short8*)&w1s[(i * 256 + tid) * 8];
    if (NEXT) {
        #pragma unroll
        for (int i = 0; i < 4; ++i)
            *(short8*)&wml[(i * 256 + tid) * 8] = *(const short8*)&wm[(i * 256 + tid) * 8];
    }
    __syncthreads();

    int wid = tid >> 6, lane = tid & 63;
    int c = lane & 15, kg = lane >> 4;

    // w2 fragments (subtiled layout) -> registers
    short8 w2f[2][4];
    #pragma unroll
    for (int ks = 0; ks < 2; ++ks)
        #pragma unroll
        for (int nt = 0; nt < 4; ++nt)
            w2f[ks][nt] = *(const short8*)&w2s[((ks * 4 + kg) * 64 + nt * 16 + c) * 8];

    float b1v[4], b2v[4], lbv[4];
    #pragma unroll
    for (int nt = 0; nt < 4; ++nt) {
        b1v[nt] = b1[nt * 16 + c];
        b2v[nt] = b2[nt * 16 + c];
        lbv[nt] = NEXT ? lbn[nt * 16 + c] : 0.f;
    }
    ushort* hl = hb[wid];

    int ebase = blockIdx.x * 256 + wid * 64;

    // ---- prologue: load tile-0 fragments ----
    short8 a[6];
    {
        int myedge = ebase + c;
        int s = src[myedge], d = dst[myedge];
        const ushort* xs = xb + (size_t)s * 64;
        const ushort* xd = xb + (size_t)d * 64;
        const ushort* ee = eb + (size_t)myedge * 64;
        a[0] = *(const short8*)(xs + kg * 8);
        a[1] = *(const short8*)(xs + 32 + kg * 8);
        a[2] = *(const short8*)(xd + kg * 8);
        a[3] = *(const short8*)(xd + 32 + kg * 8);
        a[4] = *(const short8*)(ee + kg * 8);
        a[5] = *(const short8*)(ee + 32 + kg * 8);
    }

    #pragma unroll 1
    for (int t4 = 0; t4 < 4; ++t4) {
        int e0 = ebase + t4 * 16;
        int myedge = e0 + c;

        // issue next tile's gathers at TOP (max overlap with compute below)
        short8 an[6];
        if (t4 < 3) {
            int sn = src[myedge + 16];
            int dn = dst[myedge + 16];
            const ushort* xsn = xb + (size_t)sn * 64;
            const ushort* xdn = xb + (size_t)dn * 64;
            const ushort* een = eb + (size_t)(myedge + 16) * 64;
            an[0] = *(const short8*)(xsn + kg * 8);
            an[1] = *(const short8*)(xsn + 32 + kg * 8);
            an[2] = *(const short8*)(xdn + kg * 8);
            an[3] = *(const short8*)(xdn + 32 + kg * 8);
            an[4] = *(const short8*)(een + kg * 8);
            an[5] = *(const short8*)(een + 32 + kg * 8);
        }

        // GEMM1 (w1 from LDS) on current fragments
        f32x4 acc[4];
        #pragma unroll
        for (int nt = 0; nt < 4; ++nt) acc[nt] = f32x4{b1v[nt], b1v[nt], b1v[nt], b1v[nt]};
        #pragma unroll
        for (int ks = 0; ks < 6; ++ks) {
            #pragma unroll
            for (int nt = 0; nt < 4; ++nt) {
                short8 bf = *(const short8*)&w1l[((ks * 4 + kg) * 64 + nt * 16 + c) * 8];
                acc[nt] = __builtin_amdgcn_mfma_f32_16x16x32_bf16(a[ks], bf, acc[nt], 0, 0, 0);
            }
        }
        #pragma unroll
        for (int nt = 0; nt < 4; ++nt) {
            #pragma unroll
            for (int i = 0; i < 4; ++i) {
                int rr = kg * 4 + i, cc = nt * 16 + c;
                hl[((cc >> 3) * 16 + rr) * 8 + (cc & 7)] = f2bf(fmaxf(acc[nt][i], 0.f));
            }
        }
        // GEMM2 (w2 from registers)
        f32x4 acc2[4];
        #pragma unroll
        for (int nt = 0; nt < 4; ++nt) acc2[nt] = f32x4{b2v[nt], b2v[nt], b2v[nt], b2v[nt]};
        #pragma unroll
        for (int ks = 0; ks < 2; ++ks) {
            short8 ha = *(const short8*)&hl[((ks * 4 + kg) * 16 + c) * 8];
            #pragma unroll
            for (int nt = 0; nt < 4; ++nt)
                acc2[nt] = __builtin_amdgcn_mfma_f32_16x16x32_bf16(ha, w2f[ks][nt], acc2[nt], 0, 0, 0);
        }
        // bounce update -> A-layout; e_new = e_old(regs) + 0.5*upd
        #pragma unroll
        for (int nt = 0; nt < 4; ++nt)
            #pragma unroll
            for (int i = 0; i < 4; ++i)
                hl[(kg * 4 + i) * 72 + nt * 16 + c] = f2bf(acc2[nt][i]);
        short8 u0 = *(const short8*)&hl[c * 72 + kg * 8];
        short8 u1 = *(const short8*)&hl[c * 72 + 32 + kg * 8];
        short8 en0, en1;
        #pragma unroll
        for (int j = 0; j < 8; ++j) {
            en0[j] = (short)f2bf(bf2f((ushort)a[4][j]) + 0.5f * bf2f((ushort)u0[j]));
            en1[j] = (short)f2bf(bf2f((ushort)a[5][j]) + 0.5f * bf2f((ushort)u1[j]));
        }
        *(short8*)&eb[(size_t)myedge * 64 + kg * 8]      = en0;
        *(short8*)&eb[(size_t)myedge * 64 + 32 + kg * 8] = en1;

        if (NEXT) {
            // msg_next = relu([x_s | e_new] @ wm + lbn); e_new already A-layout
            f32x4 acc3[4];
            #pragma unroll
            for (int nt = 0; nt < 4; ++nt) acc3[nt] = f32x4{lbv[nt], lbv[nt], lbv[nt], lbv[nt]};
            short8 af[4] = {a[0], a[1], en0, en1};
            #pragma unroll
            for (int ks = 0; ks < 4; ++ks) {
                #pragma unroll
                for (int nt = 0; nt < 4; ++nt) {
                    short8 bf = *(const short8*)&wml[((ks * 4 + kg) * 64 + nt * 16 + c) * 8];
                    acc3[nt] = __builtin_amdgcn_mfma_f32_16x16x32_bf16(af[ks], bf, acc3[nt], 0, 0, 0);
                }
            }
            #pragma unroll
            for (int nt = 0; nt < 4; ++nt)
                #pragma unroll
                for (int i = 0; i < 4; ++i)
                    hl[(kg * 4 + i) * 72 + nt * 16 + c] = f2bf(fmaxf(acc3[nt][i], 0.f));
            // coalesced msgbuf store (edge order)
            #pragma unroll
            for (int r = 0; r < 2; ++r) {
                int q = r * 64 + lane;
                *(short8*)&msgbuf[(size_t)(e0 + (q >> 3)) * 64 + (q & 7) * 8] =
                    *(short8*)&hl[(q >> 3) * 72 + (q & 7) * 8];
            }
        }

        // rotate pipeline
        if (t4 < 3) {
            #pragma unroll
            for (int i = 0; i < 6; ++i) a[i] = an[i];
        }
    }
}

// ======================= readout (pipelined fragment prefetch) ==============
__global__ __launch_bounds__(256) void k_readout_mfma(
    const ushort* __restrict__ xb, const ushort* __restrict__ eb,
    const int* __restrict__ src, const int* __restrict__ dst,
    const ushort* __restrict__ w1s, const float* __restrict__ b1,
    const float* __restrict__ w2, const float* __restrict__ b2,
    const float* __restrict__ w3, const float* __restrict__ b3,
    float* __restrict__ logit)
{
    __shared__ ushort w1l[192 * 64];
    __shared__ ushort hw[4][64 * 50];
    int tid = threadIdx.x;
    #pragma unroll
    for (int i = 0; i < 6; ++i)
        *(short8*)&w1l[(i * 256 + tid) * 8] = *(const short8*)&w1s[(i * 256 + tid) * 8];
    __syncthreads();

    int wid = tid >> 6, lane = tid & 63;
    int c = lane & 15, kg = lane >> 4;
    float b1v[4];
    #pragma unroll
    for (int nt = 0; nt < 4; ++nt) b1v[nt] = (nt * 16 + c < 50) ? b1[nt * 16 + c] : 0.f;

    int ebase = blockIdx.x * 256 + wid * 64;

    // prologue: tile-0 fragments (raw; brelu applied at consumption)
    short8 a[6];
    {
        int myedge = ebase + c;
        int s = src[myedge], d = dst[myedge];
        const ushort* xs = xb + (size_t)s * 64;
        const ushort* xd = xb + (size_t)d * 64;
        const ushort* ee = eb + (size_t)myedge * 64;
        a[0] = *(const short8*)(xs + kg * 8);
        a[1] = *(const short8*)(xs + 32 + kg * 8);
        a[2] = *(const short8*)(xd + kg * 8);
        a[3] = *(const short8*)(xd + 32 + kg * 8);
        a[4] = *(const short8*)(ee + kg * 8);
        a[5] = *(const short8*)(ee + 32 + kg * 8);
    }

    #pragma unroll 1
    for (int t4 = 0; t4 < 4; ++t4) {
        int e0 = ebase + t4 * 16;
        int myedge = e0 + c;

        short8 an[6];
        if (t4 < 3) {
            int sn = src[myedge + 16];
            int dn = dst[myedge + 16];
            const ushort* xsn = xb + (size_t)sn * 64;
            const ushort* xdn = xb + (size_t)dn * 64;
            const ushort* een = eb + (size_t)(myedge + 16) * 64;
            an[0] = *(const short8*)(xsn + kg * 8);
            an[1] = *(const short8*)(xsn + 32 + kg * 8);
            an[2] = *(const short8*)(xdn + kg * 8);
            an[3] = *(const short8*)(xdn + 32 + kg * 8);
            an[4] = *(const short8*)(een + kg * 8);
            an[5] = *(const short8*)(een + 32 + kg * 8);
        }

        short8 af[6];
        af[0] = brelu(a[0]); af[1] = brelu(a[1]);
        af[2] = brelu(a[2]); af[3] = brelu(a[3]);
        af[4] = a[4];        af[5] = a[5];

        f32x4 acc[4];
        #pragma unroll
        for (int nt = 0; nt < 4; ++nt) acc[nt] = f32x4{b1v[nt], b1v[nt], b1v[nt], b1v[nt]};
        #pragma unroll
        for (int ks = 0; ks < 6; ++ks) {
            #pragma unroll
            for (int nt = 0; nt < 4; ++nt) {
                short8 bf = *(const short8*)&w1l[((ks * 4 + kg) * 64 + nt * 16 + c) * 8];
                acc[nt] = __builtin_amdgcn_mfma_f32_16x16x32_bf16(af[ks], bf, acc[nt], 0, 0, 0);
            }
        }
        #pragma unroll
        for (int nt = 0; nt < 4; ++nt) {
            #pragma unroll
            for (int i = 0; i < 4; ++i) {
                int rr = kg * 4 + i, cc = nt * 16 + c;
                if (cc < 50)
                    hw[wid][(t4 * 16 + rr) * 50 + cc] = f2bf(fmaxf(acc[nt][i], 0.f));
            }
        }
        if (t4 < 3) {
            #pragma unroll
            for (int i = 0; i < 6; ++i) a[i] = an[i];
        }
    }
    int edge = blockIdx.x * 256 + wid * 64 + lane;
    const ushort* hrow = &hw[wid][lane * 50];
    float a25[25];
    #pragma unroll
    for (int j = 0; j < 25; ++j) a25[j] = b2[j];
    #pragma unroll 2
    for (int k = 0; k < 50; ++k) {
        float hv = bf2f(hrow[k]);
        #pragma unroll
        for (int j = 0; j < 25; ++j) a25[j] = fmaf(hv, w2[k * 25 + j], a25[j]);
    }
    float lg = b3[0];
    #pragma unroll
    for (int k = 0; k < 25; ++k) lg = fmaf(fmaxf(a25[k], 0.f), w3[k], lg);
    logit[edge] = lg;
}

// ---------------------------------------------------------------------------
extern "C" void kernel_launch(void* const* d_in, const int* in_sizes, int n_in,
                              void* d_out, int out_size, void* d_ws, size_t ws_size,
                              hipStream_t stream)
{
    const float* x_in  = (const float*)d_in[0];
    const float* eattr = (const float*)d_in[1];
    const int*   src   = (const int*)d_in[2];
    const int*   dst   = (const int*)d_in[3];
    const float* n_w   = (const float*)d_in[4];
    const float* n_b   = (const float*)d_in[5];
    const float* e_w   = (const float*)d_in[6];
    const float* e_b   = (const float*)d_in[7];
    const float* lw    = (const float*)d_in[8];
    const float* lb    = (const float*)d_in[9];
    const float* cw1   = (const float*)d_in[10];
    const float* cb1   = (const float*)d_in[11];
    const float* cw2   = (const float*)d_in[12];
    const float* cb2   = (const float*)d_in[13];
    const float* ew1   = (const float*)d_in[14];
    const float* eb1   = (const float*)d_in[15];
    const float* ew2   = (const float*)d_in[16];
    const float* eb2   = (const float*)d_in[17];
    const float* gam   = (const float*)d_in[18];
    const float* bet   = (const float*)d_in[19];
    const float* m1w   = (const float*)d_in[20];
    const float* m1b   = (const float*)d_in[21];
    const float* m2w   = (const float*)d_in[22];
    const float* m2b   = (const float*)d_in[23];
    const float* m3w   = (const float*)d_in[24];
    const float* m3b   = (const float*)d_in[25];

    float* xbuf  = (float*)d_out;                  // [NN,64] f32 master (output 0)
    float* logit = xbuf + (size_t)NN * 64;         // [NE]

    ushort* eb     = (ushort*)d_ws;                   // [NE,64]
    float*  tmp    = (float*)(eb + (size_t)NE * 64);  // [NN,64] h
    float*  stats  = tmp + (size_t)NN * 64;           // 512 (2 layers x 256)
    ushort* w1s    = (ushort*)(stats + 512);          // 2*192*64
    ushort* w2s    = w1s + 2 * 192 * 64;              // 2*64*64
    ushort* m1s    = w2s + 2 * 64 * 64;               // 192*64
    ushort* xb     = m1s + 192 * 64;                  // [NN,64]
    ushort* wms    = xb + (size_t)NN * 64;            // 2*128*64
    ushort* cw1s   = wms + 2 * 128 * 64;              // 2*64*64
    ushort* cw2s   = cw1s + 2 * 64 * 64;              // 2*64*64
    ushort* nws    = cw2s + 2 * 64 * 64;              // 32*64
    ushort* ews    = nws + 32 * 64;                   // 32*64
    ushort* msgbuf = ews + 32 * 64;                   // [NE,64] (EDGE order)
    int*    hist   = (int*)(msgbuf + (size_t)NE * 64);// NN
    int*    rp     = hist + NN;                       // NN+1
    int*    cursor = rp + NN + 1;                     // NN
    int*    parts  = cursor + NN;                     // 128
    int*    eidx   = parts + 128;                     // NE

    // ---- CSR build (once; reused by both layers) ----
    hipMemsetAsync(hist, 0, NN * sizeof(int), stream);
    hipMemsetAsync(stats, 0, 512 * sizeof(float), stream);
    k_hist<<<NE / 256, 256, 0, stream>>>(dst, hist);
    k_scan_part<<<NB_SCAN, 256, 0, stream>>>(hist, rp, parts);
    k_scan_tops<<<1, 128, 0, stream>>>(parts, rp);
    k_scan_add<<<(NN + 255) / 256, 256, 0, stream>>>(rp, parts, cursor);
    k_scatter<<<NE / 256, 256, 0, stream>>>(dst, cursor, eidx);

    // ---- weight prep ----
    k_w_subtile<<<48, 256, 0, stream>>>(ew1,            w1s,            192, 64);
    k_w_subtile<<<48, 256, 0, stream>>>(ew1 + 192 * 64, w1s + 192 * 64, 192, 64);
    k_w_subtile<<<16, 256, 0, stream>>>(ew2,            w2s,            64, 64);
    k_w_subtile<<<16, 256, 0, stream>>>(ew2 + 64 * 64,  w2s + 64 * 64,  64, 64);
    k_w_subtile<<<48, 256, 0, stream>>>(m1w,            m1s,            192, 50);
    k_w_msg<<<32, 256, 0, stream>>>(lw,           wms);
    k_w_msg<<<32, 256, 0, stream>>>(lw + 64 * 64, wms + 128 * 64);
    k_w_subtile<<<16, 256, 0, stream>>>(cw1,            cw1s,           64, 64);
    k_w_subtile<<<16, 256, 0, stream>>>(cw1 + 64 * 64,  cw1s + 64 * 64, 64, 64);
    k_w_subtile<<<16, 256, 0, stream>>>(cw2,            cw2s,           64, 64);
    k_w_subtile<<<16, 256, 0, stream>>>(cw2 + 64 * 64,  cw2s + 64 * 64, 64, 64);
    k_w_padk<<<8, 256, 0, stream>>>(n_w, nws, 32, 32);
    k_w_padk<<<8, 256, 0, stream>>>(e_w, ews, 16, 32);

    k_node_emb_mfma<<<(NN / 16 + 3) / 4, 256, 0, stream>>>(x_in, nws, n_b, xbuf, xb);
    // e0 + msg for layer 0 (edge-order msg store)
    k_edge_emb_fused<<<NE / 64, 256, 0, stream>>>(eattr, ews, e_b, eb,
                                                  xb, src, wms, lb, msgbuf);

    for (int l = 0; l < 2; ++l) {
        float* st = stats + l * 256;
        k_conv_csr<<<(NN / 16 + 3) / 4, 256, 0, stream>>>(
            xbuf, msgbuf, rp, eidx, tmp, cw1s + l * 64 * 64, cb1 + l * 64,
            cw2s + l * 64 * 64, cb2 + l * 64, st);
        k_bnfin<<<1, 64, 0, stream>>>(st, gam + l * 64, bet + l * 64);
        k_xupd4<<<NN * 16 / 256, 256, 0, stream>>>(xbuf, tmp, st, xb);
        if (l == 0) {
            k_emlp_fused<1><<<NE / 256, 256, 0, stream>>>(
                xb, eb, src, dst, w1s, eb1, w2s, eb2,
                wms + 128 * 64, lb + 64, msgbuf);
        } else {
            k_emlp_fused<0><<<NE / 256, 256, 0, stream>>>(
                xb, eb, src, dst, w1s + 192 * 64, eb1 + 64, w2s + 64 * 64, eb2 + 64,
                wms, lb, msgbuf);
        }
    }

    k_readout_mfma<<<NE / 256, 256, 0, stream>>>(xb, eb, src, dst,
                                                 m1s, m1b, m2w, m2b, m3w, m3b, logit);
}